// Round 13
// baseline (719.726 us; speedup 1.0000x reference)
//
#include <hip/hip_runtime.h>
#include <math.h>

#define BATCH 64
#define SEQ 16
#define DIM 2048
#define VOCAB 128000

// ---------------------------------------------------------------------------
// Kernel A: logits[b][v] = dot(hs[b,pos,:], emb[v,:]) / T[b]
// A/B experiment vs the 330us plateau: R9 geometry/schedule, but staging via
// 2-DEEP REGISTER STAGING (two named reg sets) instead of global_load_lds.
// Per step: WRITES(set_s -> lds buf) [compiler-counted vmcnt(6), no drain]
// -> LOADR(set_s, t+2) -> lgkmcnt(0) -> s_barrier -> ds_read frags -> MFMA.
// Linear coalesced global loads; XOR-swizzled ds_write dest (identical LDS
// layout to rounds 7-12 -> bit-identical logits, absmax=0 by construction).
// ---------------------------------------------------------------------------
#define BM 64
#define BN 128
#define BK 32
#define NT (DIM / BK)   // 64 k-tiles
#define ASZ (BM * BK)   // 2048 floats per A buffer (8 KB)
#define BSZ (BN * BK)   // 4096 floats per B buffer (16 KB)
#define NXCD 8

typedef __attribute__((ext_vector_type(8))) short bf16x8;
typedef __attribute__((ext_vector_type(4))) float f32x4;

__device__ __forceinline__ unsigned cvt_pk_bf16(float a, float b) {
  unsigned r;
  asm("v_cvt_pk_bf16_f32 %0, %1, %2" : "=v"(r) : "v"(a), "v"(b));
  return r;
}

// split 8 floats into hi/lo bf16x8 fragments (RTNE hi; lo = x - hi, RTNE)
__device__ __forceinline__ void split8(float4 x0, float4 x1, bf16x8* hi, bf16x8* lo) {
  float f[8] = {x0.x, x0.y, x0.z, x0.w, x1.x, x1.y, x1.z, x1.w};
  union { unsigned u[4]; bf16x8 v; } H, L;
#pragma unroll
  for (int w = 0; w < 4; ++w) {
    float a = f[2 * w], b = f[2 * w + 1];
    unsigned hp = cvt_pk_bf16(a, b);
    float ha = __uint_as_float(hp << 16);
    float hb = __uint_as_float(hp & 0xffff0000u);
    H.u[w] = hp;
    L.u[w] = cvt_pk_bf16(a - ha, b - hb);
  }
  *hi = H.v;
  *lo = L.v;
}

__global__ __launch_bounds__(256, 2) void logits_kernel(
    const float* __restrict__ emb,
    const float* __restrict__ hs,
    const int* __restrict__ pos,
    const float* __restrict__ temps,
    float* __restrict__ logits) {
  __shared__ float ldsA[2 * ASZ];  // 16 KB
  __shared__ float ldsB[2 * BSZ];  // 32 KB

  const int tid = threadIdx.x;
  const int lane = tid & 63;
  const int wid = tid >> 6;    // 4 waves
  const int lrow = lane & 15;  // fragment row selector
  const int lkb = lane >> 4;   // k-octet selector (0..3)
  const int p = pos[0];

  // ---- T1: XCD swizzle, nwg=1000 divisible by 8
  const int blk = (blockIdx.x & 7) * 125 + (blockIdx.x >> 3);
  const int vb = blk * BN + wid * 32;

  // staging lane decomposition: 8 rows x 8 chunks of 16B
  const int r8 = (lane >> 3) & 7;
  const int c8 = lane & 7;

  // LINEAR global sources; XOR-swizzled LDS write destinations
  const float* aSrc[2];
  float* aDstSw[2];
#pragma unroll
  for (int q = 0; q < 2; ++q) {
    const int g = wid * 2 + q;  // 8 A-groups of 8 rows
    aSrc[q] = hs + ((size_t)(g * 8 + r8) * SEQ + p) * DIM + 4 * c8;
    aDstSw[q] = &ldsA[(g * 8 + r8) * BK + 4 * (c8 ^ r8)];
  }
  const float* bSrc[4];
  float* bDstSw[4];
#pragma unroll
  for (int q = 0; q < 4; ++q) {
    const int g = wid * 4 + q;  // 16 B-groups of 8 rows
    bSrc[q] = emb + (size_t)(blk * BN + g * 8 + r8) * DIM + 4 * c8;
    bDstSw[q] = &ldsB[(g * 8 + r8) * BK + 4 * (c8 ^ r8)];
  }

  f32x4 acc[4][2];
#pragma unroll
  for (int i = 0; i < 4; ++i)
#pragma unroll
    for (int j = 0; j < 2; ++j) acc[i][j] = (f32x4){0.f, 0.f, 0.f, 0.f};

  // read-side swizzled float offsets (identical to rounds 7-10)
  const int sfr = 4 * (lrow & 7);
  const int off0 = (lkb * 8) ^ sfr;
  const int off1 = off0 ^ 4;

  // two named staging register sets (rule #20: static names, no runtime idx)
  float4 sa0[2], sb0[4], sa1[2], sb1[4];

#define LOADR(SA, SB, T)                                                  \
  do {                                                                    \
    const int kof_ = (T) * BK;                                            \
    _Pragma("unroll")                                                     \
    for (int q = 0; q < 2; ++q) SA[q] = *(const float4*)(aSrc[q] + kof_); \
    _Pragma("unroll")                                                     \
    for (int q = 0; q < 4; ++q) SB[q] = *(const float4*)(bSrc[q] + kof_); \
  } while (0)

#define WRITES(SA, SB, BUF)                                               \
  do {                                                                    \
    const int ao_ = (BUF) * ASZ;                                          \
    const int bo_ = (BUF) * BSZ;                                          \
    _Pragma("unroll")                                                     \
    for (int q = 0; q < 2; ++q) *(float4*)(aDstSw[q] + ao_) = SA[q];      \
    _Pragma("unroll")                                                     \
    for (int q = 0; q < 4; ++q) *(float4*)(bDstSw[q] + bo_) = SB[q];      \
  } while (0)

#define COMPUTE(BUF)                                                      \
  do {                                                                    \
    const float* A_ = &ldsA[(BUF) * ASZ];                                 \
    const float* B_ = &ldsB[(BUF) * BSZ];                                 \
    float4 ra[4][2], rb[2][2];                                            \
    _Pragma("unroll")                                                     \
    for (int i = 0; i < 4; ++i) {                                         \
      const float* rbase = &A_[(16 * i + lrow) * BK];                     \
      ra[i][0] = *(const float4*)(rbase + off0);                          \
      ra[i][1] = *(const float4*)(rbase + off1);                          \
    }                                                                     \
    _Pragma("unroll")                                                     \
    for (int j = 0; j < 2; ++j) {                                         \
      const float* rbase = &B_[(wid * 32 + 16 * j + lrow) * BK];          \
      rb[j][0] = *(const float4*)(rbase + off0);                          \
      rb[j][1] = *(const float4*)(rbase + off1);                          \
    }                                                                     \
    bf16x8 ah[4], al[4], bh[2], bl[2];                                    \
    _Pragma("unroll")                                                     \
    for (int i = 0; i < 4; ++i) split8(ra[i][0], ra[i][1], &ah[i], &al[i]);\
    _Pragma("unroll")                                                     \
    for (int j = 0; j < 2; ++j) split8(rb[j][0], rb[j][1], &bh[j], &bl[j]);\
    _Pragma("unroll")                                                     \
    for (int i = 0; i < 4; ++i)                                           \
      _Pragma("unroll")                                                   \
      for (int j = 0; j < 2; ++j) {                                       \
        acc[i][j] = __builtin_amdgcn_mfma_f32_16x16x32_bf16(ah[i], bh[j], acc[i][j], 0, 0, 0); \
        acc[i][j] = __builtin_amdgcn_mfma_f32_16x16x32_bf16(ah[i], bl[j], acc[i][j], 0, 0, 0); \
        acc[i][j] = __builtin_amdgcn_mfma_f32_16x16x32_bf16(al[i], bh[j], acc[i][j], 0, 0, 0); \
      }                                                                   \
  } while (0)

  // prologue: 2-deep register prefetch (12 loads/wave outstanding)
  LOADR(sa0, sb0, 0);
  LOADR(sa1, sb1, 1);

  for (int t = 0; t < NT; t += 2) {
    // ---- even step: set0 -> buf0
    WRITES(sa0, sb0, 0);              // compiler waits vmcnt(6): set0 landed
    if (t + 2 < NT) LOADR(sa0, sb0, t + 2);  // refill set0 (in flight 2 steps)
    asm volatile("s_waitcnt lgkmcnt(0)" ::: "memory");  // writes (+prev reads) done
    __builtin_amdgcn_sched_barrier(0);
    __builtin_amdgcn_s_barrier();
    COMPUTE(0);

    // ---- odd step: set1 -> buf1
    WRITES(sa1, sb1, 1);
    if (t + 3 < NT) LOADR(sa1, sb1, t + 3);
    asm volatile("s_waitcnt lgkmcnt(0)" ::: "memory");
    __builtin_amdgcn_sched_barrier(0);
    __builtin_amdgcn_s_barrier();
    COMPUTE(1);
  }
#undef LOADR
#undef WRITES
#undef COMPUTE

  // epilogue: C/D layout col=lane&15, row=(lane>>4)*4+reg (HW-verified)
#pragma unroll
  for (int i = 0; i < 4; ++i)
#pragma unroll
    for (int r = 0; r < 4; ++r) {
      const int b = 16 * i + lkb * 4 + r;
      const float tt = temps[b];
#pragma unroll
      for (int j = 0; j < 2; ++j) {
        const int v = vb + 16 * j + lrow;
        logits[(size_t)b * VOCAB + v] = acc[i][j][r] / tt;
      }
    }
}

// ---------------------------------------------------------------------------
// threefry2x32, 20 rounds, JAX key schedule; partitionable counter layout:
// bits(i) = o0 ^ o1 of threefry2x32(key, (0, i)).
// ---------------------------------------------------------------------------
__device__ __forceinline__ void threefry2x32(unsigned k0, unsigned k1,
                                             unsigned x0, unsigned x1,
                                             unsigned* o0, unsigned* o1) {
  const unsigned k2 = k0 ^ k1 ^ 0x1BD11BDAu;
  const unsigned ks[3] = {k0, k1, k2};
  const int rotA[4] = {13, 15, 26, 6};
  const int rotB[4] = {17, 29, 16, 24};
  x0 += k0;
  x1 += k1;
#pragma unroll
  for (int i = 0; i < 5; ++i) {
    const int* rr = (i & 1) ? rotB : rotA;
#pragma unroll
    for (int q = 0; q < 4; ++q) {
      x0 += x1;
      x1 = (x1 << rr[q]) | (x1 >> (32 - rr[q]));
      x1 ^= x0;
    }
    x0 += ks[(i + 1) % 3];
    x1 += ks[(i + 2) % 3] + (unsigned)(i + 1);
  }
  *o0 = x0;
  *o1 = x1;
}

__device__ float gumbel_noise(unsigned flat) {
  unsigned o0, o1;
  threefry2x32(0u, 42u, 0u, flat, &o0, &o1);
  unsigned bits = o0 ^ o1;
  unsigned fb = (bits >> 9) | 0x3f800000u;
  float u = __uint_as_float(fb) - 1.0f;
  const float tiny = 1.17549435e-38f;
  u = fmaxf(u, tiny);
  return -logf(-logf(u));
}

// ---------------------------------------------------------------------------
// Kernel B: per-row sampling. 64 blocks x 1024 threads.
// ---------------------------------------------------------------------------
#define CAP 4096
#define NL 12
#define NTH 1024
#define NWAVE 16

__device__ __forceinline__ unsigned sortkey(float x) {
  unsigned bits = __float_as_uint(x);
  return (bits & 0x80000000u) ? ~bits : (bits | 0x80000000u);
}
__device__ __forceinline__ float inv_sortkey(unsigned u) {
  unsigned bits = (u & 0x80000000u) ? (u & 0x7fffffffu) : ~u;
  return __uint_as_float(bits);
}

__global__ __launch_bounds__(NTH) void sample_kernel(
    const float* __restrict__ logits,
    const float* __restrict__ top_ps,
    const int* __restrict__ top_ks,
    const float* __restrict__ temps,
    const int* __restrict__ pos,
    int ws_ok,
    int* __restrict__ out) {
  const int b = blockIdx.x;
  const int tid = threadIdx.x;
  const int lane = tid & 63;
  const int wave = tid >> 6;
  const float* row = logits + (size_t)b * VOCAB;
  const float4* row4 = (const float4*)row;
  const int N4 = VOCAB / 4;

  __shared__ float sred[NWAVE];
  __shared__ int scnt_sh[NL];
  __shared__ float smax, sz;
  __shared__ float sdelta;
  __shared__ unsigned scnt;
  __shared__ unsigned ubuf[CAP];
  __shared__ unsigned ibuf[CAP];
  __shared__ unsigned sorted_u[64];
  __shared__ unsigned sorted_i[64];

  const float D[NL] = {0.5f, 0.75f, 1.0f, 1.25f, 1.5f, 1.75f,
                       2.0f, 2.5f, 3.0f, 4.0f, 8.0f, 1e30f};

  // ---- pass 1: max
  float lmax = -__builtin_huge_valf();
  for (int i = tid; i < N4; i += NTH) {
    float4 v = row4[i];
    lmax = fmaxf(fmaxf(lmax, v.x), fmaxf(fmaxf(v.y, v.z), v.w));
  }
#pragma unroll
  for (int s = 32; s > 0; s >>= 1) lmax = fmaxf(lmax, __shfl_xor(lmax, s, 64));
  if (lane == 0) sred[wave] = lmax;
  if (tid < NL) scnt_sh[tid] = 0;
  __syncthreads();
  if (tid == 0) {
    float m = sred[0];
#pragma unroll
    for (int w = 1; w < NWAVE; ++w) m = fmaxf(m, sred[w]);
    smax = m;
  }
  __syncthreads();
  const float maxl = smax;

  // ---- pass 2: Z + ladder counts
  float zsum = 0.f;
  int cnt[NL];
#pragma unroll
  for (int r = 0; r < NL; ++r) cnt[r] = 0;
  for (int i = tid; i < N4; i += NTH) {
    float4 v = row4[i];
    float xs[4] = {v.x, v.y, v.z, v.w};
#pragma unroll
    for (int c = 0; c < 4; ++c) {
      float x = xs[c];
      zsum += expf(x - maxl);
      float d = maxl - x;
#pragma unroll
      for (int r = 0; r < NL; ++r) cnt[r] += (d <= D[r]) ? 1 : 0;
    }
  }
#pragma unroll
  for (int s = 32; s > 0; s >>= 1) {
    zsum += __shfl_xor(zsum, s, 64);
#pragma unroll
    for (int r = 0; r < NL; ++r) cnt[r] += __shfl_xor(cnt[r], s, 64);
  }
  if (lane == 0) {
    sred[wave] = zsum;
#pragma unroll
    for (int r = 0; r < NL; ++r) atomicAdd(&scnt_sh[r], cnt[r]);
  }
  __syncthreads();
  if (tid == 0) {
    float z = 0.f;
#pragma unroll
    for (int w = 0; w < NWAVE; ++w) z += sred[w];
    sz = z;
    float dd = 1e30f;
#pragma unroll
    for (int r = NL - 1; r >= 0; --r)
      if (scnt_sh[r] >= 64) dd = D[r];
    sdelta = dd;
    scnt = 0;
  }
  __syncthreads();
  const float Z = sz;
  const float thrv = maxl - sdelta;

  // ---- pass 3: collect candidates
  for (int i = tid; i < N4; i += NTH) {
    float4 v = row4[i];
    float xs[4] = {v.x, v.y, v.z, v.w};
#pragma unroll
    for (int c = 0; c < 4; ++c) {
      if (xs[c] >= thrv) {
        unsigned slot = atomicAdd(&scnt, 1u);
        if (slot < CAP) {
          ubuf[slot] = sortkey(xs[c]);
          ibuf[slot] = (unsigned)(i * 4 + c);
        }
      }
    }
  }
  __syncthreads();
  const int n = (int)(scnt < (unsigned)CAP ? scnt : (unsigned)CAP);

  if (tid < 64) { sorted_u[tid] = 0u; sorted_i[tid] = 0u; }
  __syncthreads();
  for (int c = tid; c < n; c += NTH) {
    unsigned u = ubuf[c], idx = ibuf[c];
    int rank = 0;
    for (int j = 0; j < n; ++j) {
      unsigned uj = ubuf[j];
      rank += (uj > u) || (uj == u && ibuf[j] < idx);
    }
    if (rank < 64) { sorted_u[rank] = u; sorted_i[rank] = idx; }
  }
  __syncthreads();

  // ---- serial: filter + Gumbel argmax + sentinels
  if (tid == 0) {
    const float topp = top_ps[b];
    const int k = top_ks[b];
    const float tval = temps[b];
    float cum = 0.f;
    float best = -__builtin_huge_valf();
    int bestidx = 0;
    for (int r = 0; r < 64 && r < n; ++r) {
      float x = inv_sortkey(sorted_u[r]);
      float pr = expf(x - maxl) / Z;
      cum += pr;
      bool keep = (r < k) && !((cum - pr) > topp) && (pr > 0.f);
      if (keep) {
        float g = gumbel_noise((unsigned)b * (unsigned)VOCAB + sorted_i[r]);
        float sc = x + g;
        if (sc > best) { best = sc; bestidx = (int)sorted_i[r]; }
      }
    }
    int token = bestidx;

    unsigned kat0, kat1;
    threefry2x32(0u, 0u, 0u, 0u, &kat0, &kat1);
    bool inputs_ok = (pos[0] >= 0 && pos[0] < SEQ) &&
                     (tval > 0.45f && tval < 1.55f) &&
                     (topp > 0.65f && topp <= 1.0f) &&
                     (k >= 1 && k < 64);
    if (!inputs_ok) token = 3333333;
    else if (!ws_ok) token = 7777777;
    else if (kat0 != 0x6b200159u || kat1 != 0x99ba4efeu) token = 5555555;
    else if (scnt > (unsigned)CAP || n < 64) token = 4444444;
    out[b] = token;
  }
}

// ---------------------------------------------------------------------------
extern "C" void kernel_launch(void* const* d_in, const int* in_sizes, int n_in,
                              void* d_out, int out_size, void* d_ws, size_t ws_size,
                              hipStream_t stream) {
  const float* emb   = (const float*)d_in[0];
  const float* hs    = (const float*)d_in[1];
  const int*   pos   = (const int*)d_in[2];
  const float* temps = (const float*)d_in[3];
  const float* topps = (const float*)d_in[4];
  const int*   topks = (const int*)d_in[5];
  float* logits = (float*)d_ws;
  int* out = (int*)d_out;

  const size_t need = (size_t)BATCH * VOCAB * sizeof(float);
  const int ws_ok = (ws_size >= need) ? 1 : 0;

  hipLaunchKernelGGL(logits_kernel, dim3(VOCAB / BN), dim3(256), 0, stream,
                     emb, hs, pos, temps, logits);
  hipLaunchKernelGGL(sample_kernel, dim3(BATCH), dim3(NTH), 0, stream,
                     logits, topps, topks, temps, pos, ws_ok, out);
}

// Round 14
// 304.248 us; speedup vs baseline: 2.3656x; 2.3656x over previous
//
#include <hip/hip_runtime.h>
#include <math.h>

#define BATCH 64
#define SEQ 16
#define DIM 2048
#define VOCAB 128000

// ---------------------------------------------------------------------------
// Kernel A: logits[b][v] = dot(hs[b,pos,:], emb[v,:]) / T[b]
// Clean reg-staging A/B vs the gload_lds 330us plateau. All staging values in
// INDIVIDUALLY NAMED float4 scalars (no arrays -> no rule-#20 scratch demotion,
// R13's 1.5GB spill). Two named sets, 2-deep prefetch: ds_write(set a) makes
// the compiler emit a counted vmcnt staircase (set b stays outstanding, queue
// never drains). Linear coalesced global loads; XOR-swizzled ds_write dest
// (LDS layout identical to rounds 7-13 -> bit-identical logits).
// ---------------------------------------------------------------------------
#define BM 64
#define BN 128
#define BK 32
#define NT (DIM / BK)   // 64 k-tiles
#define ASZ (BM * BK)   // 2048 floats per A buffer (8 KB)
#define BSZ (BN * BK)   // 4096 floats per B buffer (16 KB)

typedef __attribute__((ext_vector_type(8))) short bf16x8;
typedef __attribute__((ext_vector_type(4))) float f32x4;

__device__ __forceinline__ unsigned cvt_pk_bf16(float a, float b) {
  unsigned r;
  asm("v_cvt_pk_bf16_f32 %0, %1, %2" : "=v"(r) : "v"(a), "v"(b));
  return r;
}

// split 8 floats into hi/lo bf16x8 fragments (RTNE hi; lo = x - hi, RTNE)
__device__ __forceinline__ void split8(float4 x0, float4 x1, bf16x8* hi, bf16x8* lo) {
  float f[8] = {x0.x, x0.y, x0.z, x0.w, x1.x, x1.y, x1.z, x1.w};
  union { unsigned u[4]; bf16x8 v; } H, L;
#pragma unroll
  for (int w = 0; w < 4; ++w) {
    float a = f[2 * w], b = f[2 * w + 1];
    unsigned hp = cvt_pk_bf16(a, b);
    float ha = __uint_as_float(hp << 16);
    float hb = __uint_as_float(hp & 0xffff0000u);
    H.u[w] = hp;
    L.u[w] = cvt_pk_bf16(a - ha, b - hb);
  }
  *hi = H.v;
  *lo = L.v;
}

__global__ __launch_bounds__(256, 2) void logits_kernel(
    const float* __restrict__ emb,
    const float* __restrict__ hs,
    const int* __restrict__ pos,
    const float* __restrict__ temps,
    float* __restrict__ logits) {
  __shared__ float ldsA[2 * ASZ];  // 16 KB
  __shared__ float ldsB[2 * BSZ];  // 32 KB

  const int tid = threadIdx.x;
  const int lane = tid & 63;
  const int wid = tid >> 6;    // 4 waves
  const int lrow = lane & 15;  // fragment row selector
  const int lkb = lane >> 4;   // k-octet selector (0..3)
  const int p = pos[0];

  // T1: XCD swizzle, nwg=1000 divisible by 8
  const int blk = (blockIdx.x & 7) * 125 + (blockIdx.x >> 3);
  const int vb = blk * BN + wid * 32;

  // staging lane decomposition: 8 rows x 8 chunks of 16B
  const int r8 = (lane >> 3) & 7;
  const int c8 = lane & 7;

  // LINEAR global sources; XOR-swizzled LDS write destinations (named, no arrays)
  const float* aS0 = hs + ((size_t)(wid * 16 + r8) * SEQ + p) * DIM + 4 * c8;
  const float* aS1 = hs + ((size_t)(wid * 16 + 8 + r8) * SEQ + p) * DIM + 4 * c8;
  float* aD0 = &ldsA[(wid * 16 + r8) * BK + 4 * (c8 ^ r8)];
  float* aD1 = &ldsA[(wid * 16 + 8 + r8) * BK + 4 * (c8 ^ r8)];
  const float* bS0 = emb + (size_t)(blk * BN + wid * 32 + r8) * DIM + 4 * c8;
  const float* bS1 = emb + (size_t)(blk * BN + wid * 32 + 8 + r8) * DIM + 4 * c8;
  const float* bS2 = emb + (size_t)(blk * BN + wid * 32 + 16 + r8) * DIM + 4 * c8;
  const float* bS3 = emb + (size_t)(blk * BN + wid * 32 + 24 + r8) * DIM + 4 * c8;
  float* bD0 = &ldsB[(wid * 32 + r8) * BK + 4 * (c8 ^ r8)];
  float* bD1 = &ldsB[(wid * 32 + 8 + r8) * BK + 4 * (c8 ^ r8)];
  float* bD2 = &ldsB[(wid * 32 + 16 + r8) * BK + 4 * (c8 ^ r8)];
  float* bD3 = &ldsB[(wid * 32 + 24 + r8) * BK + 4 * (c8 ^ r8)];

  f32x4 acc[4][2];
#pragma unroll
  for (int i = 0; i < 4; ++i)
#pragma unroll
    for (int j = 0; j < 2; ++j) acc[i][j] = (f32x4){0.f, 0.f, 0.f, 0.f};

  // read-side swizzled float offsets (identical to rounds 7-13)
  const int sfr = 4 * (lrow & 7);
  const int off0 = (lkb * 8) ^ sfr;
  const int off1 = off0 ^ 4;

  // two named staging sets (scalars only)
  float4 Aa0, Aa1, Ba0, Ba1, Ba2, Ba3;  // set a
  float4 Ab0, Ab1, Bb0, Bb1, Bb2, Bb3;  // set b

#define LOAD_A_SET(T)                           \
  do {                                          \
    const int k_ = (T) * BK;                    \
    Aa0 = *(const float4*)(aS0 + k_);           \
    Aa1 = *(const float4*)(aS1 + k_);           \
    Ba0 = *(const float4*)(bS0 + k_);           \
    Ba1 = *(const float4*)(bS1 + k_);           \
    Ba2 = *(const float4*)(bS2 + k_);           \
    Ba3 = *(const float4*)(bS3 + k_);           \
  } while (0)

#define LOAD_B_SET(T)                           \
  do {                                          \
    const int k_ = (T) * BK;                    \
    Ab0 = *(const float4*)(aS0 + k_);           \
    Ab1 = *(const float4*)(aS1 + k_);           \
    Bb0 = *(const float4*)(bS0 + k_);           \
    Bb1 = *(const float4*)(bS1 + k_);           \
    Bb2 = *(const float4*)(bS2 + k_);           \
    Bb3 = *(const float4*)(bS3 + k_);           \
  } while (0)

#define WRITE_A_SET(OFA, OFB)                   \
  do {                                          \
    *(float4*)(aD0 + (OFA)) = Aa0;              \
    *(float4*)(aD1 + (OFA)) = Aa1;              \
    *(float4*)(bD0 + (OFB)) = Ba0;              \
    *(float4*)(bD1 + (OFB)) = Ba1;              \
    *(float4*)(bD2 + (OFB)) = Ba2;              \
    *(float4*)(bD3 + (OFB)) = Ba3;              \
  } while (0)

#define WRITE_B_SET(OFA, OFB)                   \
  do {                                          \
    *(float4*)(aD0 + (OFA)) = Ab0;              \
    *(float4*)(aD1 + (OFA)) = Ab1;              \
    *(float4*)(bD0 + (OFB)) = Bb0;              \
    *(float4*)(bD1 + (OFB)) = Bb1;              \
    *(float4*)(bD2 + (OFB)) = Bb2;              \
    *(float4*)(bD3 + (OFB)) = Bb3;              \
  } while (0)

#define COMPUTE(BUF)                                                       \
  do {                                                                     \
    const float* A_ = &ldsA[(BUF) * ASZ];                                  \
    const float* B_ = &ldsB[(BUF) * BSZ];                                  \
    float4 ra[4][2], rb[2][2];                                             \
    _Pragma("unroll")                                                      \
    for (int i = 0; i < 4; ++i) {                                          \
      const float* rbase = &A_[(16 * i + lrow) * BK];                      \
      ra[i][0] = *(const float4*)(rbase + off0);                           \
      ra[i][1] = *(const float4*)(rbase + off1);                           \
    }                                                                      \
    _Pragma("unroll")                                                      \
    for (int j = 0; j < 2; ++j) {                                          \
      const float* rbase = &B_[(wid * 32 + 16 * j + lrow) * BK];           \
      rb[j][0] = *(const float4*)(rbase + off0);                           \
      rb[j][1] = *(const float4*)(rbase + off1);                           \
    }                                                                      \
    bf16x8 ah[4], al[4], bh[2], bl[2];                                     \
    _Pragma("unroll")                                                      \
    for (int i = 0; i < 4; ++i) split8(ra[i][0], ra[i][1], &ah[i], &al[i]);\
    _Pragma("unroll")                                                      \
    for (int j = 0; j < 2; ++j) split8(rb[j][0], rb[j][1], &bh[j], &bl[j]);\
    _Pragma("unroll")                                                      \
    for (int i = 0; i < 4; ++i)                                            \
      _Pragma("unroll")                                                    \
      for (int j = 0; j < 2; ++j) {                                        \
        acc[i][j] = __builtin_amdgcn_mfma_f32_16x16x32_bf16(ah[i], bh[j], acc[i][j], 0, 0, 0); \
        acc[i][j] = __builtin_amdgcn_mfma_f32_16x16x32_bf16(ah[i], bl[j], acc[i][j], 0, 0, 0); \
        acc[i][j] = __builtin_amdgcn_mfma_f32_16x16x32_bf16(al[i], bh[j], acc[i][j], 0, 0, 0); \
      }                                                                    \
  } while (0)

  // prologue: 2-deep register prefetch (12 loads/wave outstanding)
  LOAD_A_SET(0);
  LOAD_B_SET(1);

  for (int t = 0; t < NT; t += 2) {
    // ---- even step: set a -> buf0 (compiler staircase-waits only set a)
    WRITE_A_SET(0, 0);
    if (t + 2 < NT) LOAD_A_SET(t + 2);
    asm volatile("s_waitcnt lgkmcnt(0)" ::: "memory");
    __builtin_amdgcn_sched_barrier(0);
    __builtin_amdgcn_s_barrier();
    COMPUTE(0);

    // ---- odd step: set b -> buf1
    WRITE_B_SET(ASZ, BSZ);
    if (t + 3 < NT) LOAD_B_SET(t + 3);
    asm volatile("s_waitcnt lgkmcnt(0)" ::: "memory");
    __builtin_amdgcn_sched_barrier(0);
    __builtin_amdgcn_s_barrier();
    COMPUTE(1);
  }
#undef LOAD_A_SET
#undef LOAD_B_SET
#undef WRITE_A_SET
#undef WRITE_B_SET
#undef COMPUTE

  // epilogue: C/D layout col=lane&15, row=(lane>>4)*4+reg (HW-verified)
#pragma unroll
  for (int i = 0; i < 4; ++i)
#pragma unroll
    for (int r = 0; r < 4; ++r) {
      const int b = 16 * i + lkb * 4 + r;
      const float tt = temps[b];
#pragma unroll
      for (int j = 0; j < 2; ++j) {
        const int v = vb + 16 * j + lrow;
        logits[(size_t)b * VOCAB + v] = acc[i][j][r] / tt;
      }
    }
}

// ---------------------------------------------------------------------------
// threefry2x32, 20 rounds, JAX key schedule; partitionable counter layout:
// bits(i) = o0 ^ o1 of threefry2x32(key, (0, i)).
// ---------------------------------------------------------------------------
__device__ __forceinline__ void threefry2x32(unsigned k0, unsigned k1,
                                             unsigned x0, unsigned x1,
                                             unsigned* o0, unsigned* o1) {
  const unsigned k2 = k0 ^ k1 ^ 0x1BD11BDAu;
  const unsigned ks[3] = {k0, k1, k2};
  const int rotA[4] = {13, 15, 26, 6};
  const int rotB[4] = {17, 29, 16, 24};
  x0 += k0;
  x1 += k1;
#pragma unroll
  for (int i = 0; i < 5; ++i) {
    const int* rr = (i & 1) ? rotB : rotA;
#pragma unroll
    for (int q = 0; q < 4; ++q) {
      x0 += x1;
      x1 = (x1 << rr[q]) | (x1 >> (32 - rr[q]));
      x1 ^= x0;
    }
    x0 += ks[(i + 1) % 3];
    x1 += ks[(i + 2) % 3] + (unsigned)(i + 1);
  }
  *o0 = x0;
  *o1 = x1;
}

__device__ float gumbel_noise(unsigned flat) {
  unsigned o0, o1;
  threefry2x32(0u, 42u, 0u, flat, &o0, &o1);
  unsigned bits = o0 ^ o1;
  unsigned fb = (bits >> 9) | 0x3f800000u;
  float u = __uint_as_float(fb) - 1.0f;
  const float tiny = 1.17549435e-38f;
  u = fmaxf(u, tiny);
  return -logf(-logf(u));
}

// ---------------------------------------------------------------------------
// Kernel B: per-row sampling. 64 blocks x 1024 threads.
// ---------------------------------------------------------------------------
#define CAP 4096
#define NL 12
#define NTH 1024
#define NWAVE 16

__device__ __forceinline__ unsigned sortkey(float x) {
  unsigned bits = __float_as_uint(x);
  return (bits & 0x80000000u) ? ~bits : (bits | 0x80000000u);
}
__device__ __forceinline__ float inv_sortkey(unsigned u) {
  unsigned bits = (u & 0x80000000u) ? (u & 0x7fffffffu) : ~u;
  return __uint_as_float(bits);
}

__global__ __launch_bounds__(NTH) void sample_kernel(
    const float* __restrict__ logits,
    const float* __restrict__ top_ps,
    const int* __restrict__ top_ks,
    const float* __restrict__ temps,
    const int* __restrict__ pos,
    int ws_ok,
    int* __restrict__ out) {
  const int b = blockIdx.x;
  const int tid = threadIdx.x;
  const int lane = tid & 63;
  const int wave = tid >> 6;
  const float* row = logits + (size_t)b * VOCAB;
  const float4* row4 = (const float4*)row;
  const int N4 = VOCAB / 4;

  __shared__ float sred[NWAVE];
  __shared__ int scnt_sh[NL];
  __shared__ float smax, sz;
  __shared__ float sdelta;
  __shared__ unsigned scnt;
  __shared__ unsigned ubuf[CAP];
  __shared__ unsigned ibuf[CAP];
  __shared__ unsigned sorted_u[64];
  __shared__ unsigned sorted_i[64];

  const float D[NL] = {0.5f, 0.75f, 1.0f, 1.25f, 1.5f, 1.75f,
                       2.0f, 2.5f, 3.0f, 4.0f, 8.0f, 1e30f};

  // ---- pass 1: max
  float lmax = -__builtin_huge_valf();
  for (int i = tid; i < N4; i += NTH) {
    float4 v = row4[i];
    lmax = fmaxf(fmaxf(lmax, v.x), fmaxf(fmaxf(v.y, v.z), v.w));
  }
#pragma unroll
  for (int s = 32; s > 0; s >>= 1) lmax = fmaxf(lmax, __shfl_xor(lmax, s, 64));
  if (lane == 0) sred[wave] = lmax;
  if (tid < NL) scnt_sh[tid] = 0;
  __syncthreads();
  if (tid == 0) {
    float m = sred[0];
#pragma unroll
    for (int w = 1; w < NWAVE; ++w) m = fmaxf(m, sred[w]);
    smax = m;
  }
  __syncthreads();
  const float maxl = smax;

  // ---- pass 2: Z + ladder counts
  float zsum = 0.f;
  int cnt[NL];
#pragma unroll
  for (int r = 0; r < NL; ++r) cnt[r] = 0;
  for (int i = tid; i < N4; i += NTH) {
    float4 v = row4[i];
    float xs[4] = {v.x, v.y, v.z, v.w};
#pragma unroll
    for (int c = 0; c < 4; ++c) {
      float x = xs[c];
      zsum += expf(x - maxl);
      float d = maxl - x;
#pragma unroll
      for (int r = 0; r < NL; ++r) cnt[r] += (d <= D[r]) ? 1 : 0;
    }
  }
#pragma unroll
  for (int s = 32; s > 0; s >>= 1) {
    zsum += __shfl_xor(zsum, s, 64);
#pragma unroll
    for (int r = 0; r < NL; ++r) cnt[r] += __shfl_xor(cnt[r], s, 64);
  }
  if (lane == 0) {
    sred[wave] = zsum;
#pragma unroll
    for (int r = 0; r < NL; ++r) atomicAdd(&scnt_sh[r], cnt[r]);
  }
  __syncthreads();
  if (tid == 0) {
    float z = 0.f;
#pragma unroll
    for (int w = 0; w < NWAVE; ++w) z += sred[w];
    sz = z;
    float dd = 1e30f;
#pragma unroll
    for (int r = NL - 1; r >= 0; --r)
      if (scnt_sh[r] >= 64) dd = D[r];
    sdelta = dd;
    scnt = 0;
  }
  __syncthreads();
  const float Z = sz;
  const float thrv = maxl - sdelta;

  // ---- pass 3: collect candidates
  for (int i = tid; i < N4; i += NTH) {
    float4 v = row4[i];
    float xs[4] = {v.x, v.y, v.z, v.w};
#pragma unroll
    for (int c = 0; c < 4; ++c) {
      if (xs[c] >= thrv) {
        unsigned slot = atomicAdd(&scnt, 1u);
        if (slot < CAP) {
          ubuf[slot] = sortkey(xs[c]);
          ibuf[slot] = (unsigned)(i * 4 + c);
        }
      }
    }
  }
  __syncthreads();
  const int n = (int)(scnt < (unsigned)CAP ? scnt : (unsigned)CAP);

  if (tid < 64) { sorted_u[tid] = 0u; sorted_i[tid] = 0u; }
  __syncthreads();
  for (int c = tid; c < n; c += NTH) {
    unsigned u = ubuf[c], idx = ibuf[c];
    int rank = 0;
    for (int j = 0; j < n; ++j) {
      unsigned uj = ubuf[j];
      rank += (uj > u) || (uj == u && ibuf[j] < idx);
    }
    if (rank < 64) { sorted_u[rank] = u; sorted_i[rank] = idx; }
  }
  __syncthreads();

  // ---- serial: filter + Gumbel argmax + sentinels
  if (tid == 0) {
    const float topp = top_ps[b];
    const int k = top_ks[b];
    const float tval = temps[b];
    float cum = 0.f;
    float best = -__builtin_huge_valf();
    int bestidx = 0;
    for (int r = 0; r < 64 && r < n; ++r) {
      float x = inv_sortkey(sorted_u[r]);
      float pr = expf(x - maxl) / Z;
      cum += pr;
      bool keep = (r < k) && !((cum - pr) > topp) && (pr > 0.f);
      if (keep) {
        float g = gumbel_noise((unsigned)b * (unsigned)VOCAB + sorted_i[r]);
        float sc = x + g;
        if (sc > best) { best = sc; bestidx = (int)sorted_i[r]; }
      }
    }
    int token = bestidx;

    unsigned kat0, kat1;
    threefry2x32(0u, 0u, 0u, 0u, &kat0, &kat1);
    bool inputs_ok = (pos[0] >= 0 && pos[0] < SEQ) &&
                     (tval > 0.45f && tval < 1.55f) &&
                     (topp > 0.65f && topp <= 1.0f) &&
                     (k >= 1 && k < 64);
    if (!inputs_ok) token = 3333333;
    else if (!ws_ok) token = 7777777;
    else if (kat0 != 0x6b200159u || kat1 != 0x99ba4efeu) token = 5555555;
    else if (scnt > (unsigned)CAP || n < 64) token = 4444444;
    out[b] = token;
  }
}

// ---------------------------------------------------------------------------
extern "C" void kernel_launch(void* const* d_in, const int* in_sizes, int n_in,
                              void* d_out, int out_size, void* d_ws, size_t ws_size,
                              hipStream_t stream) {
  const float* emb   = (const float*)d_in[0];
  const float* hs    = (const float*)d_in[1];
  const int*   pos   = (const int*)d_in[2];
  const float* temps = (const float*)d_in[3];
  const float* topps = (const float*)d_in[4];
  const int*   topks = (const int*)d_in[5];
  float* logits = (float*)d_ws;
  int* out = (int*)d_out;

  const size_t need = (size_t)BATCH * VOCAB * sizeof(float);
  const int ws_ok = (ws_size >= need) ? 1 : 0;

  hipLaunchKernelGGL(logits_kernel, dim3(VOCAB / BN), dim3(256), 0, stream,
                     emb, hs, pos, temps, logits);
  hipLaunchKernelGGL(sample_kernel, dim3(BATCH), dim3(NTH), 0, stream,
                     logits, topps, topks, temps, pos, ws_ok, out);
}